// Round 12
// baseline (77.303 us; speedup 1.0000x reference)
//
#include <hip/hip_runtime.h>
#include <hip/hip_fp16.h>

typedef unsigned int u32;
typedef unsigned short u16;
typedef __attribute__((ext_vector_type(8))) _Float16 f16x8;
typedef __attribute__((ext_vector_type(4))) float f32x4;
typedef __attribute__((ext_vector_type(4))) u32 u32x4;

#define M_DIM 256
#define K_DIM 4096
#define N_DIM 14336
#define BM 32
#define BN 64
#define BK 64
#define NT (K_DIM / BK)      // 64 K-tiles
#define NBLK 1792            // 8 mt * 224 nt, no k-split

union U4F8 { u32x4 u; f16x8 v; };

// dequant one int32 (8 nibbles, k-order [0,4,1,5,2,6,3,7]) -> f16x8 fragment
// w = RN( RN(s*q) - z ): d2 = -1024*s is EXACT in f16 -> bit-identical to ref.
__device__ __forceinline__ f16x8 dq8(u32 q, __half2 s2, __half2 d2, __half2 z2) {
  const u32 q1 = q >> 4, q2 = q >> 8, q3 = q >> 12;
  U4F8 r;
  const u32 x0 = ( q & 0x000F000Fu) | 0x64006400u;   // {1024+n_j, 1024+n_{j+4}}
  const u32 x1 = (q1 & 0x000F000Fu) | 0x64006400u;
  const u32 x2 = (q2 & 0x000F000Fu) | 0x64006400u;
  const u32 x3 = (q3 & 0x000F000Fu) | 0x64006400u;
  r.u.x = __builtin_bit_cast(u32, __hsub2(__hfma2(__builtin_bit_cast(__half2, x0), s2, d2), z2));
  r.u.y = __builtin_bit_cast(u32, __hsub2(__hfma2(__builtin_bit_cast(__half2, x1), s2, d2), z2));
  r.u.z = __builtin_bit_cast(u32, __hsub2(__hfma2(__builtin_bit_cast(__half2, x2), s2, d2), z2));
  r.u.w = __builtin_bit_cast(u32, __hsub2(__hfma2(__builtin_bit_cast(__half2, x3), s2, d2), z2));
  return r.v;
}

__device__ __forceinline__ u32 pkrtz(float a, float b) {  // exact: x was f16
  return __builtin_bit_cast(u32, __builtin_amdgcn_cvt_pkrtz(a, b));
}

__global__ __launch_bounds__(128, 4) void kivi_gemm(
    const float* __restrict__ X,    // x upconverted to f32 [256][4096]
    const int* __restrict__ QW,     // [512][14336]; nibble j of row r -> k = r*8+j
    const float* __restrict__ S,    // [32][14336]
    const float* __restrict__ Z,    // [32][14336]
    float* __restrict__ O)          // out f32 [256][14336]
{
  // A tile only, sigma-packed f16, XOR-swizzled, double-buffered: 8 KB
  __shared__ __align__(16) u16 As[2][BM][64];

  const int tid  = threadIdx.x;
  const int lane = tid & 63;
  const int wn   = tid >> 6;        // 2 waves: n-halves of 32 cols

  // XCD swizzle: 1792 = 8*224; XCD x gets 28 consecutive nt panels x all 8 mt
  // -> QW panel reuse (8x) is L2-local (3.6 MB/XCD)
  const int b  = blockIdx.x;
  const int L  = (b & 7) * 224 + (b >> 3);
  const int nt = L >> 3;            // 0..223
  const int mt = L & 7;             // 0..7
  const int m0 = mt * BM;
  const int n0 = nt * BN;

  // wave-tile 32x32: frags 2m x 2n x 2ks (8 MFMA / K-tile)
  const int fr = lane & 15, fq = lane >> 4;
  const int cb = n0 + wn * 32 + fr;       // B col for ni=0 (ni=1 -> +16)

  // A staging: thread -> row tid>>2 (0..31), 16 f32 at k-seg (tid&3)*16
  const int arow = tid >> 2;
  const int acol = (tid & 3) * 16;
  const int awz  = (arow & 7) << 3;       // write-side XOR (u16 units)
  const int rwz  = (fr & 7) << 3;         // read-side XOR (row & 7 == fr & 7)

  f32x4 acc[2][2];
#pragma unroll
  for (int mi = 0; mi < 2; ++mi)
#pragma unroll
    for (int ni = 0; ni < 2; ++ni)
      acc[mi][ni] = (f32x4){0.f, 0.f, 0.f, 0.f};

  f32x4 aR[4];                            // A depth-1 staging
  u32 q0[2][2], q1[2][2], q2[2][2], q3[2][2];   // B depth-2: 4 static sets
  float s0[2], z0[2], s1[2], z1[2], s2[2], z2[2], s3[2], z3[2];

  auto loadAx = [&](int t) {
    const float* p = X + (size_t)(m0 + arow) * K_DIM + t * BK + acol;
    aR[0] = *(const f32x4*)(p);
    aR[1] = *(const f32x4*)(p + 4);
    aR[2] = *(const f32x4*)(p + 8);
    aR[3] = *(const f32x4*)(p + 12);
  };
  // sigma-pack pairs (j, j+4) to match dq8 k-order; 2 swizzled b128 writes
  auto writeAx = [&](int buf) {
#pragma unroll
    for (int c = 0; c < 2; ++c) {
      u32x4 pk;
      pk.x = pkrtz(aR[c * 2][0], aR[c * 2 + 1][0]);
      pk.y = pkrtz(aR[c * 2][1], aR[c * 2 + 1][1]);
      pk.z = pkrtz(aR[c * 2][2], aR[c * 2 + 1][2]);
      pk.w = pkrtz(aR[c * 2][3], aR[c * 2 + 1][3]);
      *(u32x4*)&As[buf][arow][(acol + c * 8) ^ awz] = pk;
    }
  };
  auto loadBq = [&](int t, u32 (&q)[2][2], float (&s)[2], float (&z)[2]) {
    const size_t rbase = (size_t)(t * 8 + fq) * N_DIM + cb;
#pragma unroll
    for (int ks = 0; ks < 2; ++ks)
#pragma unroll
      for (int ni = 0; ni < 2; ++ni)
        q[ks][ni] = *(const u32*)(QW + rbase + (size_t)ks * 4 * N_DIM + ni * 16);
    const int g = t >> 1;                 // GROUP_SIZE=128 = 2 K-tiles
#pragma unroll
    for (int ni = 0; ni < 2; ++ni) {
      s[ni] = S[(size_t)g * N_DIM + cb + ni * 16];
      z[ni] = Z[(size_t)g * N_DIM + cb + ni * 16];
    }
  };
  auto computeT = [&](int buf, const u32 (&q)[2][2],
                      const float (&s)[2], const float (&z)[2]) {
    const __half hneg1024 = __float2half(-1024.f);
    __half2 sh2[2], dh2[2], zh2[2];
#pragma unroll
    for (int ni = 0; ni < 2; ++ni) {
      const __half sh = __float2half(s[ni]);   // matches ref astype(f16)
      const __half zh = __float2half(z[ni]);
      const __half dh = __hmul(sh, hneg1024);  // exact: exponent shift
      sh2[ni] = __halves2half2(sh, sh);
      dh2[ni] = __halves2half2(dh, dh);
      zh2[ni] = __halves2half2(zh, zh);
    }
#pragma unroll
    for (int ks = 0; ks < 2; ++ks) {
      f16x8 af[2], bf[2];
#pragma unroll
      for (int mi = 0; mi < 2; ++mi)
        af[mi] = *(const f16x8*)&As[buf][mi * 16 + fr][(ks * 32 + fq * 8) ^ rwz];
#pragma unroll
      for (int ni = 0; ni < 2; ++ni)
        bf[ni] = dq8(q[ks][ni], sh2[ni], dh2[ni], zh2[ni]);
      __builtin_amdgcn_s_setprio(1);
#pragma unroll
      for (int mi = 0; mi < 2; ++mi)
#pragma unroll
        for (int ni = 0; ni < 2; ++ni)
          acc[mi][ni] = __builtin_amdgcn_mfma_f32_16x16x32_f16(
              af[mi], bf[ni], acc[mi][ni], 0, 0, 0);
      __builtin_amdgcn_s_setprio(0);
    }
  };

#define PHASE(T, QC, SC, ZC, QN, SN, ZN, CUR) {            \
    if ((T) + 1 < NT) loadAx((T) + 1);                     \
    if ((T) + 2 < NT) loadBq((T) + 2, QN, SN, ZN);         \
    __builtin_amdgcn_sched_barrier(0);                     \
    computeT((CUR), QC, SC, ZC);                           \
    if ((T) + 1 < NT) writeAx((CUR) ^ 1);                  \
    asm volatile("s_waitcnt lgkmcnt(0)" ::: "memory");     \
    __builtin_amdgcn_s_barrier();                          \
  }

  // prologue: A(0) -> buf0; B sets for t=0,1 in flight
  loadAx(0);
  loadBq(0, q0, s0, z0);
  loadBq(1, q1, s1, z1);
  writeAx(0);                       // vmcnt wait counts past the B loads
  asm volatile("s_waitcnt lgkmcnt(0)" ::: "memory");
  __builtin_amdgcn_s_barrier();

#pragma unroll 1
  for (int tb = 0; tb < NT; tb += 4) {
    PHASE(tb + 0, q0, s0, z0, q2, s2, z2, 0);
    PHASE(tb + 1, q1, s1, z1, q3, s3, z3, 1);
    PHASE(tb + 2, q2, s2, z2, q0, s0, z0, 0);
    PHASE(tb + 3, q3, s3, z3, q1, s1, z1, 1);
  }
#undef PHASE

  // epilogue: direct store; C/D layout col=lane&15, row=(lane>>4)*4+r
#pragma unroll
  for (int mi = 0; mi < 2; ++mi)
#pragma unroll
    for (int ni = 0; ni < 2; ++ni)
#pragma unroll
      for (int r = 0; r < 4; ++r) {
        const int row = m0 + mi * 16 + fq * 4 + r;
        const int col = n0 + wn * 32 + ni * 16 + fr;
        O[(size_t)row * N_DIM + col] = acc[mi][ni][r];
      }
}

extern "C" void kernel_launch(void* const* d_in, const int* in_sizes, int n_in,
                              void* d_out, int out_size, void* d_ws, size_t ws_size,
                              hipStream_t stream) {
  const float* X  = (const float*)d_in[0];
  const int*   QW = (const int*)d_in[1];
  const float* S  = (const float*)d_in[2];
  const float* Zp = (const float*)d_in[3];
  float* O = (float*)d_out;
  hipLaunchKernelGGL(kivi_gemm, dim3(NBLK), dim3(128), 0, stream, X, QW, S, Zp, O);
}